// Round 3
// baseline (112.420 us; speedup 1.0000x reference)
//
#include <hip/hip_runtime.h>

// RealtimeNgramProcessor R3:
//   bigram  -> 1 MB direct-map table in ws (1 L2 load)
//   trigram -> 2^18-slot open-addressing hash (key,val int2, 2 MB) (≈1.1 L2 loads)
// Tables rebuilt every launch (harness re-poisons ws; same work per call).

#define TOKEN_VOCAB 512
#define DIRECT2_ENTRIES (TOKEN_VOCAB * TOKEN_VOCAB)  // 262144 -> 1 MB
#define HASH_BITS 18
#define HASH_SLOTS (1 << HASH_BITS)                  // 262144 slots -> 2 MB
#define HASH_MASK (HASH_SLOTS - 1)

__device__ __forceinline__ unsigned hash3(int k) {
    return ((unsigned)k * 2654435761u) >> (32 - HASH_BITS);
}

__global__ void build_direct2(const int* __restrict__ keys2,
                              const int* __restrict__ vals2, int K2,
                              int* __restrict__ direct2) {
    int i = blockIdx.x * blockDim.x + threadIdx.x;
    if (i < K2) direct2[keys2[i]] = vals2[i];
}

__global__ void build_hash3(const int* __restrict__ keys3,
                            const int* __restrict__ vals3, int K3,
                            int2* __restrict__ tab) {
    int i = blockIdx.x * blockDim.x + threadIdx.x;
    if (i >= K3) return;
    int k = keys3[i], v = vals3[i];
    unsigned h = hash3(k);
    while (true) {
        int prev = atomicCAS(&tab[h].x, -1, k);
        if (prev == -1) { tab[h].y = v; break; }   // unique keys: no dup race
        h = (h + 1) & HASH_MASK;
    }
}

__global__ void ngram_encode_fast(const int* __restrict__ x,
                                  const int* __restrict__ direct2,
                                  const int2* __restrict__ tab,
                                  int* __restrict__ out, int total, int S) {
    int base = (blockIdx.x * blockDim.x + threadIdx.x) * 4;
    if (base >= total) return;
    int s = base & (S - 1);                  // base%4==0: s==0 means row start
    const int4 cur = *(const int4*)(x + base);
    int tm1 = (s >= 1) ? x[base - 1] : 0;    // left pad 0
    int tm2 = (s >= 1) ? x[base - 2] : 0;
    int t[6] = {tm2, tm1, cur.x, cur.y, cur.z, cur.w};

    int o2[4], o3[4], k3v[4];
    unsigned h[4];
    int2 slot[4];
    #pragma unroll
    for (int j = 0; j < 4; ++j) {            // all loads issued back-to-back: ILP
        int k2 = t[j + 1] * TOKEN_VOCAB + t[j + 2];
        int k3 = (t[j] * TOKEN_VOCAB + t[j + 1]) * TOKEN_VOCAB + t[j + 2];
        k3v[j] = k3;
        o2[j] = direct2[k2];
        h[j] = hash3(k3);
        slot[j] = tab[h[j]];
    }
    #pragma unroll
    for (int j = 0; j < 4; ++j) {            // resolve (extra probes are rare)
        int2 sl = slot[j];
        unsigned hh = h[j];
        while (sl.x != k3v[j] && sl.x != -1) {
            hh = (hh + 1) & HASH_MASK;
            sl = tab[hh];
        }
        o3[j] = (sl.x == k3v[j]) ? sl.y : 0;
    }
    *(int4*)(out + base)         = make_int4(o2[0], o2[1], o2[2], o2[3]);
    *(int4*)(out + total + base) = make_int4(o3[0], o3[1], o3[2], o3[3]);
}

// Fallback (ws too small): plain binary search per element.
__device__ __forceinline__ int table_lookup(const int* __restrict__ keys,
                                            const int* __restrict__ vals,
                                            int K, int packed) {
    int lo = 0, hi = K;
    while (lo < hi) {
        int mid = (lo + hi) >> 1;
        if (keys[mid] < packed) lo = mid + 1; else hi = mid;
    }
    int pos = lo < (K - 1) ? lo : (K - 1);
    return (keys[pos] == packed) ? vals[pos] : 0;
}

__global__ void ngram_encode_kernel(const int* __restrict__ x,
                                    const int* __restrict__ keys2,
                                    const int* __restrict__ vals2, int K2,
                                    const int* __restrict__ keys3,
                                    const int* __restrict__ vals3, int K3,
                                    int* __restrict__ out, int total, int S) {
    int idx = blockIdx.x * blockDim.x + threadIdx.x;
    if (idx >= total) return;
    int s = idx & (S - 1);
    int t0 = x[idx];
    int t1 = (s >= 1) ? x[idx - 1] : 0;
    int t2 = (s >= 2) ? x[idx - 2] : 0;
    int k2 = t1 * TOKEN_VOCAB + t0;
    int k3 = (t2 * TOKEN_VOCAB + t1) * TOKEN_VOCAB + t0;
    out[idx]         = table_lookup(keys2, vals2, K2, k2);
    out[total + idx] = table_lookup(keys3, vals3, K3, k3);
}

extern "C" void kernel_launch(void* const* d_in, const int* in_sizes, int n_in,
                              void* d_out, int out_size, void* d_ws, size_t ws_size,
                              hipStream_t stream) {
    const int* x     = (const int*)d_in[0];
    const int* keys2 = (const int*)d_in[1];
    const int* vals2 = (const int*)d_in[2];
    const int* keys3 = (const int*)d_in[3];
    const int* vals3 = (const int*)d_in[4];
    int* out = (int*)d_out;

    const int total = in_sizes[0];           // 256*8192
    const int S = 8192;
    const int K2 = in_sizes[1];
    const int K3 = in_sizes[3];

    const size_t ws_needed = (size_t)DIRECT2_ENTRIES * sizeof(int)
                           + (size_t)HASH_SLOTS * sizeof(int2);
    if (ws_size >= ws_needed) {
        int*  direct2 = (int*)d_ws;
        int2* tab     = (int2*)(direct2 + DIRECT2_ENTRIES);

        hipMemsetAsync(direct2, 0, DIRECT2_ENTRIES * sizeof(int), stream);
        hipMemsetAsync(tab, 0xFF, (size_t)HASH_SLOTS * sizeof(int2), stream);
        build_direct2<<<(K2 + 255) / 256, 256, 0, stream>>>(keys2, vals2, K2, direct2);
        build_hash3<<<(K3 + 255) / 256, 256, 0, stream>>>(keys3, vals3, K3, tab);

        const int block = 256;
        const int elems = total / 4;
        ngram_encode_fast<<<(elems + block - 1) / block, block, 0, stream>>>(
            x, direct2, tab, out, total, S);
    } else {
        const int block = 256;
        ngram_encode_kernel<<<(total + block - 1) / block, block, 0, stream>>>(
            x, keys2, vals2, K2, keys3, vals3, K3, out, total, S);
    }
}

// Round 4
// 103.042 us; speedup vs baseline: 1.0910x; 1.0910x over previous
//
#include <hip/hip_runtime.h>

// RealtimeNgramProcessor R4:
//   LDS filters kill ~85% of random global gathers.
//   bigram : exact 2^18-bit presence bitmap in LDS (32 KB) -> only hits (19%)
//            read global uint16 direct table (512 KB).
//   trigram: 2^18-bit Bloom (k=2, FP~10%) in LDS (32 KB) -> only ~10% probe
//            global open-addressing hash (keys int32 1 MB, vals u16 512 KB).
// Tables rebuilt every launch (harness re-poisons ws; same work per call).

#define TOKEN_VOCAB 512
#define D2_BITS 18
#define D2_ENTRIES (1 << D2_BITS)       // 262144 bigram keys
#define HB 18                           // hash + bloom index bits
#define HSLOTS (1 << HB)
#define HMASK (HSLOTS - 1)
#define BITWORDS (D2_ENTRIES / 32)      // 8192 dwords = 32 KB per filter

// ws layout (dwords):
//   [0 .. 8191]          bit2 bitmap (32 KB)
//   [8192 .. 16383]      bloom3      (32 KB)
//   then: direct2 u16 [D2_ENTRIES]   (512 KB)
//         hvals   u16 [HSLOTS]       (512 KB)
//         hkeys   s32 [HSLOTS]       (1 MB, memset 0xFF)

__device__ __forceinline__ unsigned bloom_h1(int k) {
    return ((unsigned)k * 2654435761u) >> (32 - HB);
}
__device__ __forceinline__ unsigned bloom_h2(int k) {
    return ((unsigned)k * 0x85ebca6bu) >> (32 - HB);
}
__device__ __forceinline__ unsigned hash_slot(int k) {
    return ((unsigned)k * 0xc2b2ae35u) >> (32 - HB);
}

__global__ void build2(const int* __restrict__ keys2,
                       const int* __restrict__ vals2, int K2,
                       unsigned* __restrict__ bit2,
                       unsigned short* __restrict__ d2) {
    int i = blockIdx.x * blockDim.x + threadIdx.x;
    if (i >= K2) return;
    int k = keys2[i];
    d2[k] = (unsigned short)vals2[i];
    atomicOr(&bit2[k >> 5], 1u << (k & 31));
}

__global__ void build3(const int* __restrict__ keys3,
                       const int* __restrict__ vals3, int K3,
                       unsigned* __restrict__ bloom,
                       int* __restrict__ hkeys,
                       unsigned short* __restrict__ hvals) {
    int i = blockIdx.x * blockDim.x + threadIdx.x;
    if (i >= K3) return;
    int k = keys3[i];
    unsigned b1 = bloom_h1(k), b2 = bloom_h2(k);
    atomicOr(&bloom[b1 >> 5], 1u << (b1 & 31));
    atomicOr(&bloom[b2 >> 5], 1u << (b2 & 31));
    unsigned h = hash_slot(k);
    while (true) {
        int prev = atomicCAS(&hkeys[h], -1, k);
        if (prev == -1) { hvals[h] = (unsigned short)vals3[i]; break; }
        h = (h + 1) & HMASK;
    }
}

#define THREADS 256
#define EPT 16                          // elems per thread
#define EPB (THREADS * EPT)             // 4096 elems per block

__global__ void __launch_bounds__(THREADS)
ngram_encode_fast(const int* __restrict__ x,
                  const unsigned* __restrict__ gbits,   // bit2 ++ bloom, 16384 dwords
                  const unsigned short* __restrict__ d2,
                  const int* __restrict__ hkeys,
                  const unsigned short* __restrict__ hvals,
                  int* __restrict__ out, int total, int S) {
    extern __shared__ unsigned lds[];   // [0..8191]=bit2, [8192..16383]=bloom
    // stage 64 KB of filters: 4096 int4, 16 per thread, coalesced
    {
        const int4* src = (const int4*)gbits;
        int4* dst = (int4*)lds;
        #pragma unroll
        for (int i = 0; i < 16; ++i)
            dst[threadIdx.x + i * THREADS] = src[threadIdx.x + i * THREADS];
    }
    __syncthreads();

    const int blockStart = blockIdx.x * EPB;
    #pragma unroll
    for (int g = 0; g < EPT / 4; ++g) {
        int base = blockStart + (g * THREADS + threadIdx.x) * 4;
        if (base >= total) return;
        int s = base & (S - 1);                 // base%4==0; s==0 -> row start
        const int4 cur = *(const int4*)(x + base);
        int tm1 = (s >= 1) ? x[base - 1] : 0;   // left pad 0
        int tm2 = (s >= 1) ? x[base - 2] : 0;
        int t[6] = {tm2, tm1, cur.x, cur.y, cur.z, cur.w};

        int o2[4], o3[4], k3v[4];
        bool p2[4], p3[4];
        #pragma unroll
        for (int j = 0; j < 4; ++j) {           // all LDS filter tests first (ILP)
            int k2 = t[j + 1] * TOKEN_VOCAB + t[j + 2];
            int k3 = (t[j] * TOKEN_VOCAB + t[j + 1]) * TOKEN_VOCAB + t[j + 2];
            k3v[j] = k3;
            o2[j] = k2;                          // stash k2
            p2[j] = (lds[k2 >> 5] >> (k2 & 31)) & 1u;
            unsigned b1 = bloom_h1(k3), b2 = bloom_h2(k3);
            unsigned w1 = lds[BITWORDS + (b1 >> 5)];
            unsigned w2 = lds[BITWORDS + (b2 >> 5)];
            p3[j] = ((w1 >> (b1 & 31)) & 1u) && ((w2 >> (b2 & 31)) & 1u);
        }
        #pragma unroll
        for (int j = 0; j < 4; ++j)
            o2[j] = p2[j] ? (int)d2[o2[j]] : 0;  // 19% do a u16 gather
        #pragma unroll
        for (int j = 0; j < 4; ++j) {
            int v = 0;
            if (p3[j]) {                         // ~10% probe the hash
                unsigned h = hash_slot(k3v[j]);
                int kk = hkeys[h];
                while (kk != k3v[j] && kk != -1) {
                    h = (h + 1) & HMASK;
                    kk = hkeys[h];
                }
                if (kk == k3v[j]) v = (int)hvals[h];
            }
            o3[j] = v;
        }
        *(int4*)(out + base)         = make_int4(o2[0], o2[1], o2[2], o2[3]);
        *(int4*)(out + total + base) = make_int4(o3[0], o3[1], o3[2], o3[3]);
    }
}

// Fallback (ws too small): plain binary search per element (R1, verified).
__device__ __forceinline__ int table_lookup(const int* __restrict__ keys,
                                            const int* __restrict__ vals,
                                            int K, int packed) {
    int lo = 0, hi = K;
    while (lo < hi) {
        int mid = (lo + hi) >> 1;
        if (keys[mid] < packed) lo = mid + 1; else hi = mid;
    }
    int pos = lo < (K - 1) ? lo : (K - 1);
    return (keys[pos] == packed) ? vals[pos] : 0;
}

__global__ void ngram_encode_kernel(const int* __restrict__ x,
                                    const int* __restrict__ keys2,
                                    const int* __restrict__ vals2, int K2,
                                    const int* __restrict__ keys3,
                                    const int* __restrict__ vals3, int K3,
                                    int* __restrict__ out, int total, int S) {
    int idx = blockIdx.x * blockDim.x + threadIdx.x;
    if (idx >= total) return;
    int s = idx & (S - 1);
    int t0 = x[idx];
    int t1 = (s >= 1) ? x[idx - 1] : 0;
    int t2 = (s >= 2) ? x[idx - 2] : 0;
    int k2 = t1 * TOKEN_VOCAB + t0;
    int k3 = (t2 * TOKEN_VOCAB + t1) * TOKEN_VOCAB + t0;
    out[idx]         = table_lookup(keys2, vals2, K2, k2);
    out[total + idx] = table_lookup(keys3, vals3, K3, k3);
}

extern "C" void kernel_launch(void* const* d_in, const int* in_sizes, int n_in,
                              void* d_out, int out_size, void* d_ws, size_t ws_size,
                              hipStream_t stream) {
    const int* x     = (const int*)d_in[0];
    const int* keys2 = (const int*)d_in[1];
    const int* vals2 = (const int*)d_in[2];
    const int* keys3 = (const int*)d_in[3];
    const int* vals3 = (const int*)d_in[4];
    int* out = (int*)d_out;

    const int total = in_sizes[0];          // 256*8192 = 2097152
    const int S = 8192;
    const int K2 = in_sizes[1];
    const int K3 = in_sizes[3];

    // ws layout
    unsigned*       bit2  = (unsigned*)d_ws;                      // 32 KB
    unsigned*       gbits = bit2;                                 // bit2 ++ bloom
    unsigned*       bloom = bit2 + BITWORDS;                      // 32 KB
    unsigned short* d2    = (unsigned short*)(bloom + BITWORDS);  // 512 KB
    unsigned short* hvals = d2 + D2_ENTRIES;                      // 512 KB
    int*            hkeys = (int*)(hvals + HSLOTS);               // 1 MB
    const size_t ws_needed = (size_t)(BITWORDS * 2) * 4
                           + (size_t)D2_ENTRIES * 2
                           + (size_t)HSLOTS * 2
                           + (size_t)HSLOTS * 4;
    if (ws_size >= ws_needed) {
        // zero: bit2+bloom+d2+hvals (contiguous, 64KB + 1MB); 0xFF: hkeys
        hipMemsetAsync(d_ws, 0, (size_t)(BITWORDS * 2) * 4
                                + (size_t)D2_ENTRIES * 2
                                + (size_t)HSLOTS * 2, stream);
        hipMemsetAsync(hkeys, 0xFF, (size_t)HSLOTS * 4, stream);
        build2<<<(K2 + 255) / 256, 256, 0, stream>>>(keys2, vals2, K2, bit2, d2);
        build3<<<(K3 + 255) / 256, 256, 0, stream>>>(keys3, vals3, K3, bloom, hkeys, hvals);

        int grid = (total + EPB - 1) / EPB;      // 512
        ngram_encode_fast<<<grid, THREADS, 65536, stream>>>(
            x, gbits, d2, hkeys, hvals, out, total, S);
    } else {
        ngram_encode_kernel<<<(total + 255) / 256, 256, 0, stream>>>(
            x, keys2, vals2, K2, keys3, vals3, K3, out, total, S);
    }
}

// Round 6
// 102.078 us; speedup vs baseline: 1.1013x; 1.0094x over previous
//
#include <hip/hip_runtime.h>

// RealtimeNgramProcessor R6 (structure = R2, which passed all graph checks):
//   bigram : 1 MB direct-map int32 table in ws -> 1 L2 load.
//   trigram: packed bucket meta  meta[b] = (start<<11)|count  over sorted keys3.
//            1 load; 69% of buckets empty -> done; else scan ~1.2 sorted keys.
// Tables rebuilt every launch (harness re-poisons ws; same work per call).

#define TOKEN_VOCAB 512
#define D2_ENTRIES (TOKEN_VOCAB * TOKEN_VOCAB)   // 262144 -> 1 MB int32
#define SHIFT3 10
#define NBUCKET3 (1 << 17)                       // key3 < 2^27, buckets of 2^10

__global__ void build_direct2(const int* __restrict__ keys2,
                              const int* __restrict__ vals2, int K2,
                              int* __restrict__ direct2) {
    int i = blockIdx.x * blockDim.x + threadIdx.x;
    if (i < K2) direct2[keys2[i]] = vals2[i];
}

__global__ void build_start3(const int* __restrict__ keys3, int K3,
                             int* __restrict__ start3) {
    int b = blockIdx.x * blockDim.x + threadIdx.x;
    if (b > NBUCKET3) return;
    int target = b << SHIFT3;
    int lo = 0, hi = K3;
    while (lo < hi) {
        int mid = (lo + hi) >> 1;
        if (keys3[mid] < target) lo = mid + 1; else hi = mid;
    }
    start3[b] = lo;
}

__global__ void pack_meta(const int* __restrict__ start3,
                          unsigned* __restrict__ meta) {
    int b = blockIdx.x * blockDim.x + threadIdx.x;
    if (b >= NBUCKET3) return;
    int st = start3[b];
    int cnt = start3[b + 1] - st;     // <= 1024 (bucket spans 1024 key values)
    meta[b] = ((unsigned)st << 11) | (unsigned)cnt;
}

__global__ void __launch_bounds__(256)
ngram_main(const int* __restrict__ x,
           const int* __restrict__ direct2,
           const unsigned* __restrict__ meta,
           const int* __restrict__ keys3,
           const int* __restrict__ vals3,
           int* __restrict__ out, int total, int S) {
    int base = (blockIdx.x * blockDim.x + threadIdx.x) * 4;
    if (base >= total) return;
    int s = base & (S - 1);                  // base%4==0; s==0 -> row start
    const int4 cur = *(const int4*)(x + base);
    int tm1 = (s >= 1) ? x[base - 1] : 0;    // left pad 0
    int tm2 = (s >= 1) ? x[base - 2] : 0;
    int t[6] = {tm2, tm1, cur.x, cur.y, cur.z, cur.w};

    int o2[4], k3v[4];
    unsigned m[4];
    #pragma unroll
    for (int j = 0; j < 4; ++j) {            // 8 independent loads, max ILP
        int k2 = t[j + 1] * TOKEN_VOCAB + t[j + 2];
        int k3 = (t[j] * TOKEN_VOCAB + t[j + 1]) * TOKEN_VOCAB + t[j + 2];
        k3v[j] = k3;
        o2[j] = direct2[k2];
        m[j] = meta[k3 >> SHIFT3];
    }
    int o3[4];
    #pragma unroll
    for (int j = 0; j < 4; ++j) {
        int v = 0;
        int cnt = (int)(m[j] & 2047u);
        if (cnt) {                           // ~31% of elements
            int p = (int)(m[j] >> 11);
            for (int e = 0; e < cnt; ++e) {  // sorted, avg ~1.2 iter
                int kv = keys3[p + e];
                if (kv >= k3v[j]) { if (kv == k3v[j]) v = vals3[p + e]; break; }
            }
        }
        o3[j] = v;
    }
    *(int4*)(out + base)         = make_int4(o2[0], o2[1], o2[2], o2[3]);
    *(int4*)(out + total + base) = make_int4(o3[0], o3[1], o3[2], o3[3]);
}

// Fallback (ws too small): plain binary search per element (R1, verified).
__device__ __forceinline__ int table_lookup(const int* __restrict__ keys,
                                            const int* __restrict__ vals,
                                            int K, int packed) {
    int lo = 0, hi = K;
    while (lo < hi) {
        int mid = (lo + hi) >> 1;
        if (keys[mid] < packed) lo = mid + 1; else hi = mid;
    }
    int pos = lo < (K - 1) ? lo : (K - 1);
    return (keys[pos] == packed) ? vals[pos] : 0;
}

__global__ void ngram_encode_kernel(const int* __restrict__ x,
                                    const int* __restrict__ keys2,
                                    const int* __restrict__ vals2, int K2,
                                    const int* __restrict__ keys3,
                                    const int* __restrict__ vals3, int K3,
                                    int* __restrict__ out, int total, int S) {
    int idx = blockIdx.x * blockDim.x + threadIdx.x;
    if (idx >= total) return;
    int s = idx & (S - 1);
    int t0 = x[idx];
    int t1 = (s >= 1) ? x[idx - 1] : 0;
    int t2 = (s >= 2) ? x[idx - 2] : 0;
    int k2 = t1 * TOKEN_VOCAB + t0;
    int k3 = (t2 * TOKEN_VOCAB + t1) * TOKEN_VOCAB + t0;
    out[idx]         = table_lookup(keys2, vals2, K2, k2);
    out[total + idx] = table_lookup(keys3, vals3, K3, k3);
}

extern "C" void kernel_launch(void* const* d_in, const int* in_sizes, int n_in,
                              void* d_out, int out_size, void* d_ws, size_t ws_size,
                              hipStream_t stream) {
    const int* x     = (const int*)d_in[0];
    const int* keys2 = (const int*)d_in[1];
    const int* vals2 = (const int*)d_in[2];
    const int* keys3 = (const int*)d_in[3];
    const int* vals3 = (const int*)d_in[4];
    int* out = (int*)d_out;

    const int total = in_sizes[0];           // 256*8192 = 2097152
    const int S = 8192;
    const int K2 = in_sizes[1];
    const int K3 = in_sizes[3];

    // ws layout: direct2 s32 [262144] (1 MB) | start3 s32 [NBUCKET3+1] | meta u32 [NBUCKET3]
    int*      direct2 = (int*)d_ws;
    int*      start3  = direct2 + D2_ENTRIES;
    unsigned* meta    = (unsigned*)(start3 + NBUCKET3 + 1);
    const size_t ws_needed = (size_t)(D2_ENTRIES + NBUCKET3 + 1 + NBUCKET3) * 4;

    if (ws_size >= ws_needed) {
        hipMemsetAsync(direct2, 0, (size_t)D2_ENTRIES * 4, stream);
        build_direct2<<<(K2 + 255) / 256, 256, 0, stream>>>(keys2, vals2, K2, direct2);
        build_start3<<<(NBUCKET3 + 1 + 255) / 256, 256, 0, stream>>>(keys3, K3, start3);
        pack_meta<<<(NBUCKET3 + 255) / 256, 256, 0, stream>>>(start3, meta);

        const int elems = total / 4;
        ngram_main<<<(elems + 255) / 256, 256, 0, stream>>>(
            x, direct2, meta, keys3, vals3, out, total, S);
    } else {
        ngram_encode_kernel<<<(total + 255) / 256, 256, 0, stream>>>(
            x, keys2, vals2, K2, keys3, vals3, K3, out, total, S);
    }
}